// Round 12
// baseline (391.198 us; speedup 1.0000x reference)
//
#include <hip/hip_runtime.h>

// out[b,s,k] = sum_n x[b,s,n] * W[k,n] + bias[k]
// W[k,n] = (W_q[k,n] - zeros[k,n/64]) * scales[k,n/64] * scale2[k] * mask[k,n]
// M = B*S = 8192 (rows of x), N = 4096 (reduction), K = 4096 (out features).

#define M_DIM 8192
#define N_DIM 4096
#define K_DIM 4096
#define NT 64  // K-tiles of BK=64

typedef __bf16 bf16;
typedef __attribute__((ext_vector_type(8))) bf16 bf16x8;
typedef __attribute__((ext_vector_type(4))) float f32x4;
typedef __attribute__((ext_vector_type(4))) float f32x4v;   // nontemporal builtins
typedef __attribute__((ext_vector_type(4))) int   i32x4v;

// ---------------------------------------------------------------- pre-pass 1
__global__ __launch_bounds__(256) void cvt_x_kernel(const float* __restrict__ x,
                                                    bf16* __restrict__ xb) {
  const long total = (long)M_DIM * N_DIM / 8;
  const long stride = (long)gridDim.x * blockDim.x;
  for (long t = (long)blockIdx.x * blockDim.x + threadIdx.x; t < total; t += stride) {
    const long e = t * 8;
    const f32x4v v0 = __builtin_nontemporal_load(reinterpret_cast<const f32x4v*>(x + e));
    const f32x4v v1 = __builtin_nontemporal_load(reinterpret_cast<const f32x4v*>(x + e + 4));
    bf16x8 o;
    o[0] = (bf16)v0[0]; o[1] = (bf16)v0[1]; o[2] = (bf16)v0[2]; o[3] = (bf16)v0[3];
    o[4] = (bf16)v1[0]; o[5] = (bf16)v1[1]; o[6] = (bf16)v1[2]; o[7] = (bf16)v1[3];
    *reinterpret_cast<bf16x8*>(xb + e) = o;  // xb stays cached (GEMM re-reads)
  }
}

// ---------------------------------------------------------------- pre-pass 2
__global__ __launch_bounds__(256) void deq_w_kernel(const int* __restrict__ Wq,
                                                    const float* __restrict__ scales,
                                                    const float* __restrict__ zeros,
                                                    const int* __restrict__ mask,
                                                    const float* __restrict__ scale2,
                                                    bf16* __restrict__ wb) {
  const int total = K_DIM * (N_DIM / 8);
  const int stride = gridDim.x * blockDim.x;
  for (int t = blockIdx.x * blockDim.x + threadIdx.x; t < total; t += stride) {
    const int k = t >> 9;
    const int n0 = (t & 511) << 3;
    const int g = n0 >> 6;
    const float s = scales[(k << 6) + g] * scale2[k];
    const float z = zeros[(k << 6) + g];
    const long base = (long)k * N_DIM + n0;
    const i32x4v q0 = __builtin_nontemporal_load(reinterpret_cast<const i32x4v*>(Wq + base));
    const i32x4v q1 = __builtin_nontemporal_load(reinterpret_cast<const i32x4v*>(Wq + base + 4));
    const i32x4v m0 = __builtin_nontemporal_load(reinterpret_cast<const i32x4v*>(mask + base));
    const i32x4v m1 = __builtin_nontemporal_load(reinterpret_cast<const i32x4v*>(mask + base + 4));
    bf16x8 o;
    o[0] = (bf16)(((float)q0[0] - z) * s * (float)m0[0]);
    o[1] = (bf16)(((float)q0[1] - z) * s * (float)m0[1]);
    o[2] = (bf16)(((float)q0[2] - z) * s * (float)m0[2]);
    o[3] = (bf16)(((float)q0[3] - z) * s * (float)m0[3]);
    o[4] = (bf16)(((float)q1[0] - z) * s * (float)m1[0]);
    o[5] = (bf16)(((float)q1[1] - z) * s * (float)m1[1]);
    o[6] = (bf16)(((float)q1[2] - z) * s * (float)m1[2]);
    o[7] = (bf16)(((float)q1[3] - z) * s * (float)m1[3]);
    *reinterpret_cast<bf16x8*>(wb + base) = o;  // wb stays cached
  }
}

// ---------------------------------------------------------------- GEMM
// 128x128 tile, BK=64, 4 waves (2Mx2N), 64 KiB dbuf LDS -> 2 BLOCKS/CU
// co-resident: independent blocks cover each other's barrier/drain stalls
// (cross-block overlap, m114 mechanism). Schedule = round-11 2-phase
// structure verbatim (LGKM0-before-barrier WAR, VM8/VM8 counted ledger,
// prologue-14/VM6, tail VM2/VM0) with resized offsets; stage-load counts
// per phase are unchanged (PH0: 2, PH1: 6) so the vmcnt ledger is identical.
//
// LDS per buffer (16384 elem): A [0,8192) = 128 rows x 64 cols bf16,
// B [8192,16384). Row = 128 B; swizzle byte = row*128 + x*16,
// x = slot ^ (row&7). Staged via inverse-permuted global source.
//
// A-half h = mh=h rows of both wr: {h*32..+32} u {64+h*32..+32}
//   (afH0 read at PH1(s-1) prefetch; afH1 read at PH0(s))
// B-half h = rows [h*64,+64)  (ALL B frags read at PH1(s-1) prefetch)
// Stages: PH0(s): Ah1(s+1)->other; PH1(s): Ah0(s+2)+Bfull(s+2)->cur.
// Every region overwritten >=2 phases after its unique read phase.
__device__ inline void gload16(const bf16* g, bf16* l) {
  __builtin_amdgcn_global_load_lds(
      (const __attribute__((address_space(1))) void*)g,
      (__attribute__((address_space(3))) void*)l, 16, 0, 0);
}

#define BARRIER asm volatile("s_barrier" ::: "memory")
#define LGKM0   asm volatile("s_waitcnt lgkmcnt(0)" ::: "memory")
#define VM8     asm volatile("s_waitcnt vmcnt(8)" ::: "memory")
#define VM6     asm volatile("s_waitcnt vmcnt(6)" ::: "memory")
#define VM2     asm volatile("s_waitcnt vmcnt(2)" ::: "memory")
#define VM0     asm volatile("s_waitcnt vmcnt(0)" ::: "memory")
#define SBAR    __builtin_amdgcn_sched_barrier(0)

__global__ __launch_bounds__(256, 2) void gemm_kernel(const bf16* __restrict__ xb,
                                                      const bf16* __restrict__ wb,
                                                      const float* __restrict__ bias,
                                                      float* __restrict__ out) {
  __shared__ bf16 lds[32768];  // 64 KiB: 2 buffers x (8K A + 8K B) elements

  const int tid = threadIdx.x;
  const int lane = tid & 63;
  const int w = tid >> 6;
  const int wr = w >> 1;  // 0..1  (M half, 64 rows)
  const int wc = w & 1;   // 0..1  (N half, 64 cols)

  // XCD mapping: xcd = gid&7 owns 8 bm x 32 bk, bk-minor ->
  // A-panel (1 MB) L2-resident per bm-group; B streams from L3.
  const int gid = blockIdx.x;
  const int idx = gid >> 3;                   // 0..255
  const int bm = (gid & 7) * 8 + (idx >> 5);  // 64 M-tiles
  const int bk = idx & 31;                    // 32 K-tiles
  const long m0 = (long)bm * 128;
  const long k0 = (long)bk * 128;

  // ---- staging source decode (inverse swizzle), per-thread constants.
  // A: banded (wrb = tid>>7 selects wr-band); 2 gloads/half, 16 rows each.
  const int wrb = tid >> 7;                        // 0..1
  const int u7 = tid & 127;
  const int slotA = (u7 & 7) ^ ((u7 >> 3) & 7);
  const bf16* baseA = xb + (m0 + wrb * 64 + (u7 >> 3)) * N_DIM + slotA * 8;
  // B: flat rows; 2 gloads/half, 32 rows each.
  const int slotB = (tid & 7) ^ ((tid >> 3) & 7);
  const bf16* baseB = wb + (k0 + (tid >> 3)) * N_DIM + slotB * 8;

  // ---- ds_read fragment bases. Lane: row += (lane&15); k-slot = kk*4+(lane>>4);
  // x = (kk*4 + (lane>>4)) ^ (lane&7)  [row&7 == lane&7 for all frag rows].
  const int ln15 = lane & 15;
  const int x0 = (lane >> 4) ^ (lane & 7);
  int aoffk[2], boffk[2];
#pragma unroll
  for (int kk = 0; kk < 2; ++kk) {
    const int x = x0 ^ (kk << 2);
    aoffk[kk] = (wr * 64 + ln15) * 64 + x * 8;          // + mh*2048 + mf*1024
    boffk[kk] = 8192 + (wc * 64 + ln15) * 64 + x * 8;   // + nh*2048 + nf*1024
  }

  f32x4 acc[4][4] = {};
  bf16x8 afH0[2][2], afH1[2][2], bfA[2][2], bfB[2][2];

  auto STA = [&](int tt, int bsel, int h) {  // stage A-half h (mh=h rows, both wr)
#pragma unroll
    for (int g = 0; g < 2; ++g)
      gload16(baseA + (long)(h * 32 + g * 16) * N_DIM + tt * 64,
              lds + bsel * 16384 + wrb * 4096 + h * 2048 + g * 1024 + u7 * 8);
  };
  auto STB = [&](int tt, int bsel, int h) {  // stage B-half h = rows [h*64,+64)
#pragma unroll
    for (int g = 0; g < 2; ++g)
      gload16(baseB + (long)(h * 64 + g * 32) * N_DIM + tt * 64,
              lds + bsel * 16384 + 8192 + h * 4096 + g * 2048 + (tid << 3));
  };
  auto LDA = [&](bf16x8 (*dst)[2], int cb, int mh) {
#pragma unroll
    for (int mf = 0; mf < 2; ++mf)
#pragma unroll
      for (int kk = 0; kk < 2; ++kk)
        dst[mf][kk] = *reinterpret_cast<const bf16x8*>(
            lds + cb + aoffk[kk] + mh * 2048 + mf * 1024);
  };
  auto LDB1 = [&](bf16x8* dst, int cb, int nh, int nf) {
#pragma unroll
    for (int kk = 0; kk < 2; ++kk)
      dst[kk] = *reinterpret_cast<const bf16x8*>(
          lds + cb + boffk[kk] + nh * 2048 + nf * 1024);
  };
  auto MFMA_Q = [&](bf16x8 (*a2)[2], bf16x8 (*bf)[2], int mh, int nh) {
#pragma unroll
    for (int kk = 0; kk < 2; ++kk)
#pragma unroll
      for (int mf = 0; mf < 2; ++mf)
#pragma unroll
        for (int nf = 0; nf < 2; ++nf)
          acc[mh * 2 + mf][nh * 2 + nf] = __builtin_amdgcn_mfma_f32_16x16x32_bf16(
              a2[mf][kk], bf[nf][kk], acc[mh * 2 + mf][nh * 2 + nf], 0, 0, 0);
  };

  // Prologue: tile0 {Ah0,Bh0,Bh1,Ah1}, tile1 {Ah0,Bh0,Bh1} (14 loads).
  // VM6 retires tile0's 8; prefetch tile0's afH0/bfA/bfB from buf0.
  STA(0, 0, 0); STB(0, 0, 0); STB(0, 0, 1); STA(0, 0, 1);
  STA(1, 1, 0); STB(1, 1, 0); STB(1, 1, 1);
  VM6; BARRIER;
  LDA(afH0, 0, 0);
  LDB1(bfA[0], 0, 0, 0); LDB1(bfA[1], 0, 0, 1);
  LDB1(bfB[0], 0, 1, 0); LDB1(bfB[1], 0, 1, 1);

  for (int s = 0; s < NT; ++s) {
    const int c = s & 1;
    const int cb = c * 16384;
    const int ob = (c ^ 1) * 16384;
    // ---- PH0: MFMA mh0 x {nh0,nh1} (afH0 x bfA/bfB) + load afH1(cur);
    //      stage Ah1(s+1)->other.
    if (s + 1 < NT) { STA(s + 1, c ^ 1, 1); VM8; } else { VM0; }
    LGKM0;            // drains PH1(s-1)'s prefetch reads (afH0/bfA/bfB)
    BARRIER; SBAR;
    __builtin_amdgcn_s_setprio(1);
    LDA(afH1, cb, 1);
    MFMA_Q(afH0, bfA, 0, 0);
    MFMA_Q(afH0, bfB, 0, 1);
    __builtin_amdgcn_s_setprio(0);
    // ---- PH1: MFMA mh1 x {nh0,nh1} (afH1 x bfA/bfB) + prefetch next tile's
    //      afH0/bfA/bfB from other buf; stage Ah0/Bh0/Bh1(s+2)->cur.
    if (s + 2 < NT) { STA(s + 2, c, 0); STB(s + 2, c, 0); STB(s + 2, c, 1); VM8; }
    else if (s + 1 < NT) { VM2; }
    LGKM0;            // drains PH0's LDA afH1
    BARRIER; SBAR;
    __builtin_amdgcn_s_setprio(1);
    if (s + 1 < NT) LDA(afH0, ob, 0);
    MFMA_Q(afH1, bfA, 1, 0);
    if (s + 1 < NT) { LDB1(bfA[0], ob, 0, 0); LDB1(bfA[1], ob, 0, 1); }  // WAR: after consume
    MFMA_Q(afH1, bfB, 1, 1);
    if (s + 1 < NT) { LDB1(bfB[0], ob, 1, 0); LDB1(bfB[1], ob, 1, 1); }
    __builtin_amdgcn_s_setprio(0);
  }

  // Epilogue. C/D: col = lane&15 (K-dim), row = (lane>>4)*4 + r (M-dim).
  // Non-temporal stores: out is write-once, keep xb/wb cached instead.
  const int ocol0 = (int)k0 + wc * 64 + ln15;
  const int orow0 = (int)m0 + wr * 64 + (lane >> 4) * 4;
#pragma unroll
  for (int ni = 0; ni < 4; ++ni) {
    const float bv = bias[ocol0 + ni * 16];
#pragma unroll
    for (int mi = 0; mi < 4; ++mi)
#pragma unroll
      for (int r = 0; r < 4; ++r)
        __builtin_nontemporal_store(
            acc[mi][ni][r] + bv,
            &out[(long)(orow0 + mi * 16 + r) * K_DIM + ocol0 + ni * 16]);
  }
}

// ---------------------------------------------------------------- launch
extern "C" void kernel_launch(void* const* d_in, const int* in_sizes, int n_in,
                              void* d_out, int out_size, void* d_ws, size_t ws_size,
                              hipStream_t stream) {
  const float* x      = (const float*)d_in[0];
  const int*   Wq     = (const int*)d_in[1];
  const float* scales = (const float*)d_in[2];
  const float* zeros  = (const float*)d_in[3];
  const int*   mask   = (const int*)d_in[4];
  const float* scale2 = (const float*)d_in[5];
  const float* bias   = (const float*)d_in[6];
  float* out = (float*)d_out;

  bf16* xb = (bf16*)d_ws;
  bf16* wb = (bf16*)((char*)d_ws + (size_t)M_DIM * N_DIM * 2);

  cvt_x_kernel<<<2048, 256, 0, stream>>>(x, xb);
  deq_w_kernel<<<2048, 256, 0, stream>>>(Wq, scales, zeros, mask, scale2, wb);

  // Grid: (M/128) * (K/128) = 64 * 32 = 2048 blocks, 256 threads.
  gemm_kernel<<<2048, 256, 0, stream>>>(xb, wb, bias, out);
}

// Round 14
// 343.297 us; speedup vs baseline: 1.1395x; 1.1395x over previous
//
#include <hip/hip_runtime.h>

// out[b,s,k] = sum_n x[b,s,n] * W[k,n] + bias[k]
// W[k,n] = (W_q[k,n] - zeros[k,n/64]) * scales[k,n/64] * scale2[k] * mask[k,n]
// M = B*S = 8192 (rows of x), N = 4096 (reduction), K = 4096 (out features).

#define M_DIM 8192
#define N_DIM 4096
#define K_DIM 4096
#define NT 64  // K-tiles of BK=64

typedef __bf16 bf16;
typedef __attribute__((ext_vector_type(8))) bf16 bf16x8;
typedef __attribute__((ext_vector_type(4))) float f32x4;
typedef __attribute__((ext_vector_type(4))) float f32x4v;   // nontemporal builtins
typedef __attribute__((ext_vector_type(4))) int   i32x4v;

// ------------------------------------------------- fused pre-pass
// Blocks [0,2048): x f32 -> bf16.  Blocks [2048,3072): dequant W -> bf16.
__global__ __launch_bounds__(256) void prep_kernel(const float* __restrict__ x,
                                                   bf16* __restrict__ xb,
                                                   const int* __restrict__ Wq,
                                                   const float* __restrict__ scales,
                                                   const float* __restrict__ zeros,
                                                   const int* __restrict__ mask,
                                                   const float* __restrict__ scale2,
                                                   bf16* __restrict__ wb) {
  if (blockIdx.x < 2048) {
    const long total = (long)M_DIM * N_DIM / 8;
    const long stride = (long)2048 * 256;
    for (long t = (long)blockIdx.x * 256 + threadIdx.x; t < total; t += stride) {
      const long e = t * 8;
      const f32x4v v0 = __builtin_nontemporal_load(reinterpret_cast<const f32x4v*>(x + e));
      const f32x4v v1 = __builtin_nontemporal_load(reinterpret_cast<const f32x4v*>(x + e + 4));
      bf16x8 o;
      o[0] = (bf16)v0[0]; o[1] = (bf16)v0[1]; o[2] = (bf16)v0[2]; o[3] = (bf16)v0[3];
      o[4] = (bf16)v1[0]; o[5] = (bf16)v1[1]; o[6] = (bf16)v1[2]; o[7] = (bf16)v1[3];
      *reinterpret_cast<bf16x8*>(xb + e) = o;  // xb stays cached (GEMM re-reads)
    }
  } else {
    const int total = K_DIM * (N_DIM / 8);
    const int stride = 1024 * 256;
    for (int t = (blockIdx.x - 2048) * 256 + threadIdx.x; t < total; t += stride) {
      const int k = t >> 9;
      const int n0 = (t & 511) << 3;
      const int g = n0 >> 6;
      const float s = scales[(k << 6) + g] * scale2[k];
      const float z = zeros[(k << 6) + g];
      const long base = (long)k * N_DIM + n0;
      const i32x4v q0 = __builtin_nontemporal_load(reinterpret_cast<const i32x4v*>(Wq + base));
      const i32x4v q1 = __builtin_nontemporal_load(reinterpret_cast<const i32x4v*>(Wq + base + 4));
      const i32x4v m0 = __builtin_nontemporal_load(reinterpret_cast<const i32x4v*>(mask + base));
      const i32x4v m1 = __builtin_nontemporal_load(reinterpret_cast<const i32x4v*>(mask + base + 4));
      bf16x8 o;
      o[0] = (bf16)(((float)q0[0] - z) * s * (float)m0[0]);
      o[1] = (bf16)(((float)q0[1] - z) * s * (float)m0[1]);
      o[2] = (bf16)(((float)q0[2] - z) * s * (float)m0[2]);
      o[3] = (bf16)(((float)q0[3] - z) * s * (float)m0[3]);
      o[4] = (bf16)(((float)q1[0] - z) * s * (float)m1[0]);
      o[5] = (bf16)(((float)q1[1] - z) * s * (float)m1[1]);
      o[6] = (bf16)(((float)q1[2] - z) * s * (float)m1[2]);
      o[7] = (bf16)(((float)q1[3] - z) * s * (float)m1[3]);
      *reinterpret_cast<bf16x8*>(wb + base) = o;  // wb stays cached
    }
  }
}

// ---------------------------------------------------------------- GEMM
// Round-11 schedule verbatim (2 phases/K-tile, LGKM0-before-barrier WAR,
// VM8/VM8 counted ledger, prologue-14/VM6, tail VM2/VM0, reg-frag dbuf,
// 0-conflict swizzle, A-panel-resident XCD map) with issue-slot diet:
// loop-carried stage pointers (+64 elem/tile) and compile-time buffer
// parity (TILE unrolled x2). Buffer 1 = element offset 32768 (fixed: round
// 13 prologue staged tile1 at +16384 = buffer0's B region -> NaN).
__device__ inline void gload16(const bf16* g, bf16* l) {
  __builtin_amdgcn_global_load_lds(
      (const __attribute__((address_space(1))) void*)g,
      (__attribute__((address_space(3))) void*)l, 16, 0, 0);
}

#define BARRIER asm volatile("s_barrier" ::: "memory")
#define LGKM0   asm volatile("s_waitcnt lgkmcnt(0)" ::: "memory")
#define VM8     asm volatile("s_waitcnt vmcnt(8)" ::: "memory")
#define VM6     asm volatile("s_waitcnt vmcnt(6)" ::: "memory")
#define VM2     asm volatile("s_waitcnt vmcnt(2)" ::: "memory")
#define VM0     asm volatile("s_waitcnt vmcnt(0)" ::: "memory")
#define SBAR    __builtin_amdgcn_sched_barrier(0)

__global__ __launch_bounds__(512, 2) void gemm_kernel(const bf16* __restrict__ xb,
                                                      const bf16* __restrict__ wb,
                                                      const float* __restrict__ bias,
                                                      float* __restrict__ out) {
  __shared__ bf16 lds[65536];  // 128 KiB: 2 buffers x (16K A + 16K B) elements

  const int tid = threadIdx.x;
  const int lane = tid & 63;
  const int w = tid >> 6;
  const int wr = w >> 2;  // 0..1  (M half, 128 rows)
  const int wc = w & 3;   // 0..3  (N quarter, 64 cols)

  // XCD mapping: xcd = gid&7 owns bm in [xcd*4, xcd*4+4), all bk.
  const int gid = blockIdx.x;
  const int idx = gid >> 3;                   // 0..63
  const int bm = (gid & 7) * 4 + (idx >> 4);  // 32 M-tiles
  const int bk = idx & 15;                    // 16 K-tiles
  const long m0 = (long)bm * 256;
  const long k0 = (long)bk * 256;

  // ---- staging source decode (inverse swizzle), per-thread constants.
  const int browA = tid >> 3;                      // 0..63
  const int slotA = (tid & 7) ^ (browA & 7);
  const bf16* baseA = xb + (m0 + browA) * N_DIM + slotA * 8;
  const int u = tid & 255;
  const int wcb = tid >> 8;                        // 0..1
  const int browB = u >> 3;                        // 0..31
  const int slotB = (u & 7) ^ (browB & 7);
  const bf16* baseB = wb + (k0 + wcb * 64 + browB) * N_DIM + slotB * 8;

  // Loop-carried stage sources (bumped +64 elem = 128 B per tile).
  // PH0 stages Ah1(t+1): init at tt=1. PH1 stages Ah0/Bh0/Bh1(t+2): init tt=2.
  const bf16* sA1a = baseA + (long)64  * N_DIM + 64;
  const bf16* sA1b = baseA + (long)192 * N_DIM + 64;
  const bf16* sA0a = baseA                     + 128;
  const bf16* sA0b = baseA + (long)128 * N_DIM + 128;
  const bf16* sB0a = baseB                     + 128;
  const bf16* sB0b = baseB + (long)128 * N_DIM + 128;
  const bf16* sB1a = baseB + (long)32  * N_DIM + 128;
  const bf16* sB1b = baseB + (long)160 * N_DIM + 128;

  // LDS staging destinations (constant per buffer parity).
  bf16* const dT = lds + (tid << 3);                        // A dst base
  bf16* const dB = lds + 16384 + wcb * 4096 + (u << 3);     // B dst base

  // ---- ds_read fragment bases.
  const int ln15 = lane & 15;
  const int x0 = (lane >> 4) ^ (lane & 7);
  int aoffk[2], boffk[2];
#pragma unroll
  for (int kk = 0; kk < 2; ++kk) {
    const int x = x0 ^ (kk << 2);
    aoffk[kk] = (wr * 128 + ln15) * 64 + x * 8;
    boffk[kk] = 16384 + (wc * 64 + ln15) * 64 + x * 8;
  }

  f32x4 acc[8][4] = {};
  bf16x8 afH0[4][2], afH1[4][2], bfA[2][2], bfB[2][2];

  auto LDA = [&](bf16x8 (*dst)[2], int cb, int mh) {
#pragma unroll
    for (int mf = 0; mf < 4; ++mf)
#pragma unroll
      for (int kk = 0; kk < 2; ++kk)
        dst[mf][kk] = *reinterpret_cast<const bf16x8*>(
            lds + cb + aoffk[kk] + mh * 4096 + mf * 1024);
  };
  auto LDB1 = [&](bf16x8* dst, int cb, int nh, int nf) {
#pragma unroll
    for (int kk = 0; kk < 2; ++kk)
      dst[kk] = *reinterpret_cast<const bf16x8*>(
          lds + cb + boffk[kk] + nh * 2048 + nf * 1024);
  };
  auto MFMA_Q = [&](bf16x8 (*a4)[2], bf16x8 (*bf)[2], int mh, int nh) {
#pragma unroll
    for (int kk = 0; kk < 2; ++kk)
#pragma unroll
      for (int mf = 0; mf < 4; ++mf)
#pragma unroll
        for (int nf = 0; nf < 2; ++nf)
          acc[mh * 4 + mf][nh * 2 + nf] = __builtin_amdgcn_mfma_f32_16x16x32_bf16(
              a4[mf][kk], bf[nf][kk], acc[mh * 4 + mf][nh * 2 + nf], 0, 0, 0);
  };

  // Prologue (FIFO = consumption order): tile0 {Ah0,Bh0,Bh1,Ah1} -> buf0,
  // tile1 {Ah0,Bh0,Bh1} -> buf1 (+32768) = 14 loads; VM6 retires tile0's 8.
  gload16(baseA,                        dT);
  gload16(baseA + (long)128 * N_DIM,    dT + 8192);
  gload16(baseB,                        dB);
  gload16(baseB + (long)128 * N_DIM,    dB + 8192);
  gload16(baseB + (long)32  * N_DIM,    dB + 2048);
  gload16(baseB + (long)160 * N_DIM,    dB + 2048 + 8192);
  gload16(baseA + (long)64  * N_DIM,    dT + 4096);
  gload16(baseA + (long)192 * N_DIM,    dT + 4096 + 8192);
  gload16(baseA + 64,                       dT + 32768);
  gload16(baseA + (long)128 * N_DIM + 64,   dT + 32768 + 8192);
  gload16(baseB + 64,                       dB + 32768);
  gload16(baseB + (long)128 * N_DIM + 64,   dB + 32768 + 8192);
  gload16(baseB + (long)32  * N_DIM + 64,   dB + 32768 + 2048);
  gload16(baseB + (long)160 * N_DIM + 64,   dB + 32768 + 2048 + 8192);
  VM6; BARRIER;
  LDA(afH0, 0, 0);
  LDB1(bfA[0], 0, 0, 0); LDB1(bfA[1], 0, 0, 1);
  LDB1(bfB[0], 0, 1, 0); LDB1(bfB[1], 0, 1, 1);

  auto TILE = [&](int t, int c) {   // c is a literal at every call site
    const int cb = c * 32768;
    const int ob = (c ^ 1) * 32768;
    // ---- PH0: MFMA mh0 x {nh0,nh1} + load afH1(cur); stage Ah1(t+1)->other.
    if (t + 1 < NT) {
      gload16(sA1a, dT + ob + 4096);
      gload16(sA1b, dT + ob + 4096 + 8192);
      VM8;
    } else { VM0; }
    LGKM0;            // drains PH1(t-1)'s prefetch reads
    BARRIER; SBAR;
    __builtin_amdgcn_s_setprio(1);
    LDA(afH1, cb, 1);
    MFMA_Q(afH0, bfA, 0, 0);
    MFMA_Q(afH0, bfB, 0, 1);
    __builtin_amdgcn_s_setprio(0);
    // ---- PH1: MFMA mh1 x {nh0,nh1} + prefetch next tile's afH0/bfA/bfB;
    //      stage Ah0/Bh0/Bh1(t+2)->cur.
    if (t + 2 < NT) {
      gload16(sA0a, dT + cb);
      gload16(sA0b, dT + cb + 8192);
      gload16(sB0a, dB + cb);
      gload16(sB0b, dB + cb + 8192);
      gload16(sB1a, dB + cb + 2048);
      gload16(sB1b, dB + cb + 2048 + 8192);
      VM8;
    } else if (t + 1 < NT) { VM2; }
    LGKM0;            // drains PH0's LDA afH1
    BARRIER; SBAR;
    __builtin_amdgcn_s_setprio(1);
    if (t + 1 < NT) LDA(afH0, ob, 0);
    MFMA_Q(afH1, bfA, 1, 0);
    if (t + 1 < NT) { LDB1(bfA[0], ob, 0, 0); LDB1(bfA[1], ob, 0, 1); }  // WAR: after consume
    MFMA_Q(afH1, bfB, 1, 1);
    if (t + 1 < NT) { LDB1(bfB[0], ob, 1, 0); LDB1(bfB[1], ob, 1, 1); }
    __builtin_amdgcn_s_setprio(0);
    // advance stage pointers (+64 elements = next K-tile)
    sA1a += 64; sA1b += 64; sA0a += 64; sA0b += 64;
    sB0a += 64; sB0b += 64; sB1a += 64; sB1b += 64;
  };

  for (int tp = 0; tp < NT / 2; ++tp) {
    TILE(2 * tp, 0);
    TILE(2 * tp + 1, 1);
  }

  // Epilogue. C/D: col = lane&15 (K-dim), row = (lane>>4)*4 + r (M-dim).
  const int ocol0 = (int)k0 + wc * 64 + ln15;
  const int orow0 = (int)m0 + wr * 128 + (lane >> 4) * 4;
#pragma unroll
  for (int ni = 0; ni < 4; ++ni) {
    const float bv = bias[ocol0 + ni * 16];
#pragma unroll
    for (int mi = 0; mi < 8; ++mi)
#pragma unroll
      for (int r = 0; r < 4; ++r)
        __builtin_nontemporal_store(
            acc[mi][ni][r] + bv,
            &out[(long)(orow0 + mi * 16 + r) * K_DIM + ocol0 + ni * 16]);
  }
}

// ---------------------------------------------------------------- launch
extern "C" void kernel_launch(void* const* d_in, const int* in_sizes, int n_in,
                              void* d_out, int out_size, void* d_ws, size_t ws_size,
                              hipStream_t stream) {
  const float* x      = (const float*)d_in[0];
  const int*   Wq     = (const int*)d_in[1];
  const float* scales = (const float*)d_in[2];
  const float* zeros  = (const float*)d_in[3];
  const int*   mask   = (const int*)d_in[4];
  const float* scale2 = (const float*)d_in[5];
  const float* bias   = (const float*)d_in[6];
  float* out = (float*)d_out;

  bf16* xb = (bf16*)d_ws;
  bf16* wb = (bf16*)((char*)d_ws + (size_t)M_DIM * N_DIM * 2);

  prep_kernel<<<3072, 256, 0, stream>>>(x, xb, Wq, scales, zeros, mask, scale2, wb);

  // Grid: (M/256) * (K/256) = 32 * 16 = 512 blocks, 512 threads.
  gemm_kernel<<<512, 512, 0, stream>>>(xb, wb, bias, out);
}

// Round 15
// 276.184 us; speedup vs baseline: 1.4164x; 1.2430x over previous
//
#include <hip/hip_runtime.h>

// out[b,s,k] = sum_n x[b,s,n] * W[k,n] + bias[k]
// W[k,n] = (W_q[k,n] - zeros[k,n/64]) * scales[k,n/64] * scale2[k] * mask[k,n]
// M = B*S = 8192 (rows of x), N = 4096 (reduction), K = 4096 (out features).

#define M_DIM 8192
#define N_DIM 4096
#define K_DIM 4096
#define NT 64  // K-tiles of BK=64

typedef __bf16 bf16;
typedef __attribute__((ext_vector_type(8))) bf16 bf16x8;
typedef __attribute__((ext_vector_type(4))) float f32x4;
typedef __attribute__((ext_vector_type(4))) float f32x4v;   // nontemporal builtins
typedef __attribute__((ext_vector_type(4))) int   i32x4v;

// ------------------------------------------------- fused pre-pass
// Blocks [0,2048): x f32 -> bf16.  Blocks [2048,3072): dequant W -> bf16.
// (Validated round 14: overhead 58 -> 39 us; independent of the GEMM.)
__global__ __launch_bounds__(256) void prep_kernel(const float* __restrict__ x,
                                                   bf16* __restrict__ xb,
                                                   const int* __restrict__ Wq,
                                                   const float* __restrict__ scales,
                                                   const float* __restrict__ zeros,
                                                   const int* __restrict__ mask,
                                                   const float* __restrict__ scale2,
                                                   bf16* __restrict__ wb) {
  if (blockIdx.x < 2048) {
    const long total = (long)M_DIM * N_DIM / 8;
    const long stride = (long)2048 * 256;
    for (long t = (long)blockIdx.x * 256 + threadIdx.x; t < total; t += stride) {
      const long e = t * 8;
      const f32x4v v0 = __builtin_nontemporal_load(reinterpret_cast<const f32x4v*>(x + e));
      const f32x4v v1 = __builtin_nontemporal_load(reinterpret_cast<const f32x4v*>(x + e + 4));
      bf16x8 o;
      o[0] = (bf16)v0[0]; o[1] = (bf16)v0[1]; o[2] = (bf16)v0[2]; o[3] = (bf16)v0[3];
      o[4] = (bf16)v1[0]; o[5] = (bf16)v1[1]; o[6] = (bf16)v1[2]; o[7] = (bf16)v1[3];
      *reinterpret_cast<bf16x8*>(xb + e) = o;  // xb stays cached (GEMM re-reads)
    }
  } else {
    const int total = K_DIM * (N_DIM / 8);
    const int stride = 1024 * 256;
    for (int t = (blockIdx.x - 2048) * 256 + threadIdx.x; t < total; t += stride) {
      const int k = t >> 9;
      const int n0 = (t & 511) << 3;
      const int g = n0 >> 6;
      const float s = scales[(k << 6) + g] * scale2[k];
      const float z = zeros[(k << 6) + g];
      const long base = (long)k * N_DIM + n0;
      const i32x4v q0 = __builtin_nontemporal_load(reinterpret_cast<const i32x4v*>(Wq + base));
      const i32x4v q1 = __builtin_nontemporal_load(reinterpret_cast<const i32x4v*>(Wq + base + 4));
      const i32x4v m0 = __builtin_nontemporal_load(reinterpret_cast<const i32x4v*>(mask + base));
      const i32x4v m1 = __builtin_nontemporal_load(reinterpret_cast<const i32x4v*>(mask + base + 4));
      bf16x8 o;
      o[0] = (bf16)(((float)q0[0] - z) * s * (float)m0[0]);
      o[1] = (bf16)(((float)q0[1] - z) * s * (float)m0[1]);
      o[2] = (bf16)(((float)q0[2] - z) * s * (float)m0[2]);
      o[3] = (bf16)(((float)q0[3] - z) * s * (float)m0[3]);
      o[4] = (bf16)(((float)q1[0] - z) * s * (float)m1[0]);
      o[5] = (bf16)(((float)q1[1] - z) * s * (float)m1[1]);
      o[6] = (bf16)(((float)q1[2] - z) * s * (float)m1[2]);
      o[7] = (bf16)(((float)q1[3] - z) * s * (float)m1[3]);
      *reinterpret_cast<bf16x8*>(wb + base) = o;  // wb stays cached
    }
  }
}

// ---------------------------------------------------------------- GEMM
// Round-11 kernel VERBATIM (best measured: 221 us, MfmaUtil 56.6%, 0 bank
// conflicts). 2 phases per K-tile, LGKM0-before-barrier WAR rule, VM8/VM8
// counted ledger, prologue-14/VM6, tail VM2/VM0, reg-frag double-buffering,
// 0-conflict swizzle, A-panel-resident XCD map, nt epilogue stores.
__device__ inline void gload16(const bf16* g, bf16* l) {
  __builtin_amdgcn_global_load_lds(
      (const __attribute__((address_space(1))) void*)g,
      (__attribute__((address_space(3))) void*)l, 16, 0, 0);
}

#define BARRIER asm volatile("s_barrier" ::: "memory")
#define LGKM0   asm volatile("s_waitcnt lgkmcnt(0)" ::: "memory")
#define VM8     asm volatile("s_waitcnt vmcnt(8)" ::: "memory")
#define VM6     asm volatile("s_waitcnt vmcnt(6)" ::: "memory")
#define VM2     asm volatile("s_waitcnt vmcnt(2)" ::: "memory")
#define VM0     asm volatile("s_waitcnt vmcnt(0)" ::: "memory")
#define SBAR    __builtin_amdgcn_sched_barrier(0)

__global__ __launch_bounds__(512, 2) void gemm_kernel(const bf16* __restrict__ xb,
                                                      const bf16* __restrict__ wb,
                                                      const float* __restrict__ bias,
                                                      float* __restrict__ out) {
  __shared__ bf16 lds[65536];  // 128 KiB: 2 buffers x (16K A + 16K B) elements

  const int tid = threadIdx.x;
  const int lane = tid & 63;
  const int w = tid >> 6;
  const int wr = w >> 2;  // 0..1  (M half, 128 rows)
  const int wc = w & 3;   // 0..3  (N quarter, 64 cols)

  // XCD mapping: xcd = gid&7 owns bm in [xcd*4, xcd*4+4), all bk.
  const int gid = blockIdx.x;
  const int idx = gid >> 3;                   // 0..63
  const int bm = (gid & 7) * 4 + (idx >> 4);  // 32 M-tiles
  const int bk = idx & 15;                    // 16 K-tiles
  const long m0 = (long)bm * 256;
  const long k0 = (long)bk * 256;

  // ---- staging source decode (inverse swizzle), per-thread constants.
  const int browA = tid >> 3;                      // 0..63
  const int slotA = (tid & 7) ^ (browA & 7);
  const bf16* baseA = xb + (m0 + browA) * N_DIM + slotA * 8;
  const int u = tid & 255;
  const int wcb = tid >> 8;                        // 0..1
  const int browB = u >> 3;                        // 0..31
  const int slotB = (u & 7) ^ (browB & 7);
  const bf16* baseB = wb + (k0 + wcb * 64 + browB) * N_DIM + slotB * 8;

  // ---- ds_read fragment bases.
  const int ln15 = lane & 15;
  const int x0 = (lane >> 4) ^ (lane & 7);
  int aoffk[2], boffk[2];
#pragma unroll
  for (int kk = 0; kk < 2; ++kk) {
    const int x = x0 ^ (kk << 2);
    aoffk[kk] = (wr * 128 + ln15) * 64 + x * 8;
    boffk[kk] = 16384 + (wc * 64 + ln15) * 64 + x * 8;
  }

  f32x4 acc[8][4] = {};
  bf16x8 afH0[4][2], afH1[4][2], bfA[2][2], bfB[2][2];

  auto STA = [&](int tt, int bsel, int h) {  // stage A-half h of tile tt
    const bf16* s = baseA + (long)(h * 64) * N_DIM + tt * 64;
    bf16* d = lds + bsel * 32768 + h * 4096 + (tid << 3);
    gload16(s, d);
    gload16(s + (long)128 * N_DIM, d + 8192);
  };
  auto STB = [&](int tt, int bsel, int h) {  // stage B-half h of tile tt
    const bf16* s = baseB + (long)(h * 32) * N_DIM + tt * 64;
    bf16* d = lds + bsel * 32768 + 16384 + wcb * 4096 + h * 2048 + (u << 3);
    gload16(s, d);
    gload16(s + (long)128 * N_DIM, d + 8192);
  };
  auto LDA = [&](bf16x8 (*dst)[2], int cb, int mh) {
#pragma unroll
    for (int mf = 0; mf < 4; ++mf)
#pragma unroll
      for (int kk = 0; kk < 2; ++kk)
        dst[mf][kk] = *reinterpret_cast<const bf16x8*>(
            lds + cb + aoffk[kk] + mh * 4096 + mf * 1024);
  };
  auto LDB1 = [&](bf16x8* dst, int cb, int nh, int nf) {  // one nf column
#pragma unroll
    for (int kk = 0; kk < 2; ++kk)
      dst[kk] = *reinterpret_cast<const bf16x8*>(
          lds + cb + boffk[kk] + nh * 2048 + nf * 1024);
  };
  auto MFMA_Q = [&](bf16x8 (*a4)[2], bf16x8 (*bf)[2], int mh, int nh) {
#pragma unroll
    for (int kk = 0; kk < 2; ++kk)
#pragma unroll
      for (int mf = 0; mf < 4; ++mf)
#pragma unroll
        for (int nf = 0; nf < 2; ++nf)
          acc[mh * 4 + mf][nh * 2 + nf] = __builtin_amdgcn_mfma_f32_16x16x32_bf16(
              a4[mf][kk], bf[nf][kk], acc[mh * 4 + mf][nh * 2 + nf], 0, 0, 0);
  };

  // Prologue: tile0 {Ah0,Bh0,Bh1,Ah1}, tile1 {Ah0,Bh0,Bh1} (14 loads).
  // VM6 retires tile0's 8; prefetch tile0's afH0/bfA/bfB from buf0.
  STA(0, 0, 0); STB(0, 0, 0); STB(0, 0, 1); STA(0, 0, 1);
  STA(1, 1, 0); STB(1, 1, 0); STB(1, 1, 1);
  VM6; BARRIER;
  LDA(afH0, 0, 0);
  LDB1(bfA[0], 0, 0, 0); LDB1(bfA[1], 0, 0, 1);
  LDB1(bfB[0], 0, 1, 0); LDB1(bfB[1], 0, 1, 1);

  for (int s = 0; s < NT; ++s) {
    const int c = s & 1;
    const int cb = c * 32768;
    const int ob = (c ^ 1) * 32768;
    // ---- PH0: MFMA mh0 x {nh0,nh1} (afH0 x bfA/bfB) + load afH1(cur);
    //      stage Ah1(s+1)->other.
    if (s + 1 < NT) { STA(s + 1, c ^ 1, 1); VM8; } else { VM0; }
    LGKM0;            // drains PH1(s-1)'s prefetch reads (afH0/bfA/bfB)
    BARRIER; SBAR;
    __builtin_amdgcn_s_setprio(1);
    LDA(afH1, cb, 1);
    MFMA_Q(afH0, bfA, 0, 0);
    MFMA_Q(afH0, bfB, 0, 1);
    __builtin_amdgcn_s_setprio(0);
    // ---- PH1: MFMA mh1 x {nh0,nh1} (afH1 x bfA/bfB) + prefetch next tile's
    //      afH0/bfA/bfB from other buf; stage Ah0/Bh0/Bh1(s+2)->cur.
    if (s + 2 < NT) { STA(s + 2, c, 0); STB(s + 2, c, 0); STB(s + 2, c, 1); VM8; }
    else if (s + 1 < NT) { VM2; }
    LGKM0;            // drains PH0's LDA afH1
    BARRIER; SBAR;
    __builtin_amdgcn_s_setprio(1);
    if (s + 1 < NT) LDA(afH0, ob, 0);          // no reg conflict with PH1 MFMA
    MFMA_Q(afH1, bfA, 1, 0);
    if (s + 1 < NT) { LDB1(bfA[0], ob, 0, 0); LDB1(bfA[1], ob, 0, 1); }  // WAR: after consume
    MFMA_Q(afH1, bfB, 1, 1);
    if (s + 1 < NT) { LDB1(bfB[0], ob, 1, 0); LDB1(bfB[1], ob, 1, 1); }
    __builtin_amdgcn_s_setprio(0);
  }

  // Epilogue. C/D: col = lane&15 (K-dim), row = (lane>>4)*4 + r (M-dim).
  // Non-temporal stores: out is write-once, keep xb/wb cached instead.
  const int ocol0 = (int)k0 + wc * 64 + ln15;
  const int orow0 = (int)m0 + wr * 128 + (lane >> 4) * 4;
#pragma unroll
  for (int ni = 0; ni < 4; ++ni) {
    const float bv = bias[ocol0 + ni * 16];
#pragma unroll
    for (int mi = 0; mi < 8; ++mi)
#pragma unroll
      for (int r = 0; r < 4; ++r)
        __builtin_nontemporal_store(
            acc[mi][ni][r] + bv,
            &out[(long)(orow0 + mi * 16 + r) * K_DIM + ocol0 + ni * 16]);
  }
}

// ---------------------------------------------------------------- launch
extern "C" void kernel_launch(void* const* d_in, const int* in_sizes, int n_in,
                              void* d_out, int out_size, void* d_ws, size_t ws_size,
                              hipStream_t stream) {
  const float* x      = (const float*)d_in[0];
  const int*   Wq     = (const int*)d_in[1];
  const float* scales = (const float*)d_in[2];
  const float* zeros  = (const float*)d_in[3];
  const int*   mask   = (const int*)d_in[4];
  const float* scale2 = (const float*)d_in[5];
  const float* bias   = (const float*)d_in[6];
  float* out = (float*)d_out;

  bf16* xb = (bf16*)d_ws;
  bf16* wb = (bf16*)((char*)d_ws + (size_t)M_DIM * N_DIM * 2);

  prep_kernel<<<3072, 256, 0, stream>>>(x, xb, Wq, scales, zeros, mask, scale2, wb);

  // Grid: (M/256) * (K/256) = 32 * 16 = 512 blocks, 512 threads.
  gemm_kernel<<<512, 512, 0, stream>>>(xb, wb, bias, out);
}